// Round 1
// baseline (35779.184 us; speedup 1.0000x reference)
//
#include <hip/hip_runtime.h>

// ============================================================================
// Transformer_72816875537065: 3-layer fp32 encoder + 512-step autoregressive
// pointer decoder with exact JAX threefry PRNG replication.
//
// PRNG assumption (modern JAX default, jax_threefry_partitionable=True):
//   step key  i : (k1,k2) = threefry2x32((0,42), x0=0, x1=i)
//   bits[b,n] at step i: (h1,h2) = threefry2x32(key_i, 0, b*512+n); bits=h1^h2
//   u = max(tiny, bitcast((bits>>9)|0x3f800000)-1 + tiny); g=-log(-log(u))
//   action = argmax(logits + g)  (first index on ties)
// If actions come back scrambled, switch to legacy split-halves counters.
//
// All fp32 on purpose: sampled actions are argmax over gumbel-perturbed
// logits; bf16 noise would flip argmax winners and cascade.
// ============================================================================

#define NEGINF (-__builtin_huge_valf())
#define TINYF 1.17549435e-38f

__device__ __forceinline__ unsigned rotl32(unsigned v, int r) {
  return (v << r) | (v >> (32 - r));
}

__device__ __forceinline__ void threefry2x32(unsigned k0, unsigned k1,
                                             unsigned& x0, unsigned& x1) {
  unsigned k2 = k0 ^ k1 ^ 0x1BD11BDAu;
  x0 += k0; x1 += k1;
#define TF_R(r) { x0 += x1; x1 = rotl32(x1, (r)); x1 ^= x0; }
  TF_R(13) TF_R(15) TF_R(26) TF_R(6)
  x0 += k1; x1 += k2 + 1u;
  TF_R(17) TF_R(29) TF_R(16) TF_R(24)
  x0 += k2; x1 += k0 + 2u;
  TF_R(13) TF_R(15) TF_R(26) TF_R(6)
  x0 += k0; x1 += k1 + 3u;
  TF_R(17) TF_R(29) TF_R(16) TF_R(24)
  x0 += k1; x1 += k2 + 4u;
  TF_R(13) TF_R(15) TF_R(26) TF_R(6)
  x0 += k2; x1 += k0 + 5u;
#undef TF_R
}

// ---------------------------------------------------------------------------
// x = problems @ embed_W + embed_b     [32768,2]@[2,128]
// ---------------------------------------------------------------------------
__global__ __launch_bounds__(256) void k_embed(const float* __restrict__ P,
                                               const float* __restrict__ eW,
                                               const float* __restrict__ eb,
                                               float* __restrict__ X) {
  int idx = blockIdx.x * 256 + threadIdx.x;     // 0 .. 32768*128-1
  int row = idx >> 7, d = idx & 127;
  X[idx] = P[row * 2] * eW[d] + P[row * 2 + 1] * eW[128 + d] + eb[d];
}

// ---------------------------------------------------------------------------
// C[M,128] = A[M,128] @ W[128,128]  (+ residual R)
// 16x16 output tile per 256-thread block, full-K staged in LDS.
// ---------------------------------------------------------------------------
__global__ __launch_bounds__(256) void k_gemm128(const float* __restrict__ A,
                                                 const float* __restrict__ W,
                                                 const float* __restrict__ R,
                                                 float* __restrict__ C, int M) {
  __shared__ float As[16][129];   // +1 pad: kills 4-way conflict on As[ty][k]
  __shared__ float Ws[128][17];
  const int tx = threadIdx.x & 15, ty = threadIdx.x >> 4;
  const int row0 = blockIdx.x * 16, col0 = blockIdx.y * 16;
  for (int idx = threadIdx.x; idx < 2048; idx += 256) {
    int r = idx >> 7, k = idx & 127;
    As[r][k] = (row0 + r < M) ? A[(size_t)(row0 + r) * 128 + k] : 0.0f;
    int kk = idx >> 4, c = idx & 15;
    Ws[kk][c] = W[(size_t)kk * 128 + col0 + c];
  }
  __syncthreads();
  float acc = 0.0f;
#pragma unroll 8
  for (int k = 0; k < 128; ++k) acc += As[ty][k] * Ws[k][tx];
  const int row = row0 + ty, col = col0 + tx;
  if (row < M) {
    if (R) acc += R[(size_t)row * 128 + col];
    C[(size_t)row * 128 + col] = acc;
  }
}

// ---------------------------------------------------------------------------
// Encoder self-attention, one block per (b,h). K/V slices staged in LDS
// with stride-17 padding (a [512][16] layout is a 32-way bank conflict).
// ---------------------------------------------------------------------------
__global__ __launch_bounds__(256) void k_attn_enc(const float* __restrict__ Q,
                                                  const float* __restrict__ K,
                                                  const float* __restrict__ V,
                                                  float* __restrict__ O) {
  const int b = blockIdx.x >> 3, h = blockIdx.x & 7;
  const int t = threadIdx.x, l = t & 63, w = t >> 6;
  __shared__ float Ks[512][17];
  __shared__ float Vs[512][17];
  __shared__ float p[512];
  __shared__ float qv[16];
  __shared__ float wred[8];
  __shared__ float part[16][17];
  const size_t base = (size_t)b * 512 * 128 + (size_t)h * 16;
  for (int idx = t; idx < 512 * 16; idx += 256) {
    int n = idx >> 4, d = idx & 15;
    Ks[n][d] = K[base + (size_t)n * 128 + d];
    Vs[n][d] = V[base + (size_t)n * 128 + d];
  }
  __syncthreads();
  for (int q = 0; q < 512; ++q) {
    if (t < 16) qv[t] = Q[base + (size_t)q * 128 + t];
    __syncthreads();
    float s0 = 0.0f, s1 = 0.0f;
#pragma unroll
    for (int d = 0; d < 16; ++d) {
      float qd = qv[d];
      s0 += qd * Ks[t][d];
      s1 += qd * Ks[t + 256][d];
    }
    s0 *= 0.25f; s1 *= 0.25f;
    float m = fmaxf(s0, s1);
    for (int o = 32; o; o >>= 1) m = fmaxf(m, __shfl_xor(m, o));
    if (l == 0) wred[w] = m;
    __syncthreads();
    m = fmaxf(fmaxf(wred[0], wred[1]), fmaxf(wred[2], wred[3]));
    float e0 = expf(s0 - m), e1 = expf(s1 - m);
    p[t] = e0; p[t + 256] = e1;
    float sum = e0 + e1;
    for (int o = 32; o; o >>= 1) sum += __shfl_xor(sum, o);
    if (l == 0) wred[4 + w] = sum;
    __syncthreads();
    const float inv = 1.0f / (wred[4] + wred[5] + wred[6] + wred[7]);
    const int d = t & 15, g = t >> 4;             // g in 0..15
    float acc = 0.0f;
    for (int j = 0; j < 32; ++j) {
      int n = g + 16 * j;
      acc += p[n] * Vs[n][d];
    }
    part[g][d] = acc;
    __syncthreads();
    if (t < 16) {
      float a2 = 0.0f;
#pragma unroll
      for (int gg = 0; gg < 16; ++gg) a2 += part[gg][t];
      O[base + (size_t)q * 128 + t] = a2 * inv;
    }
    __syncthreads();
  }
}

// ---------------------------------------------------------------------------
// LayerNorm over last dim (128). 1 wave per row, 4 rows per block.
// ---------------------------------------------------------------------------
__global__ __launch_bounds__(256) void k_ln(const float* __restrict__ Y,
                                            const float* __restrict__ g,
                                            const float* __restrict__ bb,
                                            float* __restrict__ O, int M) {
  const int row = blockIdx.x * 4 + (threadIdx.x >> 6);
  const int l = threadIdx.x & 63;
  if (row >= M) return;
  const float* y = Y + (size_t)row * 128;
  float v0 = y[l], v1 = y[l + 64];
  float s = v0 + v1;
  for (int o = 32; o; o >>= 1) s += __shfl_xor(s, o);
  const float mu = s * (1.0f / 128.0f);
  float d0 = v0 - mu, d1 = v1 - mu;
  float q = d0 * d0 + d1 * d1;
  for (int o = 32; o; o >>= 1) q += __shfl_xor(q, o);
  const float sd = sqrtf(q * (1.0f / 128.0f) + 1e-6f);
  O[(size_t)row * 128 + l]      = d0 / sd * g[l] + bb[l];
  O[(size_t)row * 128 + l + 64] = d1 / sd * g[l + 64] + bb[l + 64];
}

// ---------------------------------------------------------------------------
// Fused FFN: Y = relu(X@W1 + b1)@W2 + b2 + X      (8 rows per block)
// ---------------------------------------------------------------------------
__global__ __launch_bounds__(256) void k_ffn(const float* __restrict__ X,
                                             const float* __restrict__ W1,
                                             const float* __restrict__ b1,
                                             const float* __restrict__ W2,
                                             const float* __restrict__ b2,
                                             float* __restrict__ Y) {
  __shared__ float xr[8][129];
  __shared__ float hbuf[8][513];
  const int t = threadIdx.x;
  const size_t row0 = (size_t)blockIdx.x * 8;
  for (int idx = t; idx < 1024; idx += 256) {
    int r = idx >> 7, d = idx & 127;
    xr[r][d] = X[(row0 + r) * 128 + d];
  }
  __syncthreads();
  for (int j = t; j < 512; j += 256) {
    float acc[8] = {0, 0, 0, 0, 0, 0, 0, 0};
    const float* wp = W1 + j;
    for (int k = 0; k < 128; ++k) {
      float wv = wp[(size_t)k * 512];
#pragma unroll
      for (int r = 0; r < 8; ++r) acc[r] += xr[r][k] * wv;
    }
    float bj = b1[j];
#pragma unroll
    for (int r = 0; r < 8; ++r) hbuf[r][j] = fmaxf(acc[r] + bj, 0.0f);
  }
  __syncthreads();
  {
    const int o = t & 127, r0 = t >> 7;
    float acc[4] = {0, 0, 0, 0};
    const float* wp = W2 + o;
    for (int k = 0; k < 512; ++k) {
      float wv = wp[(size_t)k * 128];
#pragma unroll
      for (int u = 0; u < 4; ++u) acc[u] += hbuf[r0 + 2 * u][k] * wv;
    }
    float bo = b2[o];
#pragma unroll
    for (int u = 0; u < 4; ++u) {
      int r = r0 + 2 * u;
      Y[(row0 + r) * 128 + o] = acc[u] + bo + xr[r][o];
    }
  }
}

// ---------------------------------------------------------------------------
// node_mean[b,:] = mean_n X[b,n,:]
// ---------------------------------------------------------------------------
__global__ __launch_bounds__(128) void k_mean(const float* __restrict__ X,
                                              float* __restrict__ NM) {
  const int b = blockIdx.x, d = threadIdx.x;
  float s = 0.0f;
  for (int n = 0; n < 512; ++n) s += X[((size_t)b * 512 + n) * 128 + d];
  NM[b * 128 + d] = s * (1.0f / 512.0f);
}

// ---------------------------------------------------------------------------
// Persistent decoder: 1 block per batch, 512 threads (8 waves), 512 steps.
// ---------------------------------------------------------------------------
__global__ __launch_bounds__(512) void k_decoder(
    const float* __restrict__ X,    // node_context [64,512,128]
    const float* __restrict__ KD,   // X @ dec_Wk
    const float* __restrict__ VD,   // X @ dec_Wv
    const float* __restrict__ KN,   // X @ node_W
    const float* __restrict__ GC,   // graph_context [64,128]
    const float* __restrict__ Wq,   // dec_Wq [384,128]
    const float* __restrict__ Wo,   // dec_Wo [128,128]
    const float* __restrict__ Wvf, const float* __restrict__ Wvl,
    float* __restrict__ out_probs, float* __restrict__ out_act) {
  const int b = blockIdx.x;
  const int t = threadIdx.x;
  const int l = t & 63, w = t >> 6;

  __shared__ float cq[384], qp[128], att[128], qf[128];
  __shared__ float part[4][128];
  __shared__ float l_lds[512];
  __shared__ float p_lds[8][512];
  __shared__ float gl[128], lastv[128], firstv[128];
  __shared__ unsigned char mask[512];
  __shared__ uint2 keys[512];
  __shared__ float redZ[8]; __shared__ int redI[8];
  __shared__ float redM[8]; __shared__ float redD[8];
  __shared__ int action_s; __shared__ float M_s;

  {   // step keys: foldlike split of key(42): TF((0,42), 0, i)
    unsigned x0 = 0u, x1 = (unsigned)t;
    threefry2x32(0u, 42u, x0, x1);
    keys[t] = make_uint2(x0, x1);
    mask[t] = 0;
  }
  if (t < 128) { gl[t] = GC[b * 128 + t]; lastv[t] = Wvl[t]; firstv[t] = Wvf[t]; }
  __syncthreads();

  const float* Kb  = KD + (size_t)b * 512 * 128;
  const float* Vb  = VD + (size_t)b * 512 * 128;
  const float* knb = KN + (size_t)b * 512 * 128;

  for (int i = 0; i < 512; ++i) {
    // (1) cq = [graph_context, last, first]
    if (t < 384) cq[t] = (t < 128) ? gl[t] : (t < 256 ? lastv[t - 128] : firstv[t - 256]);
    __syncthreads();
    // (2) qp = cq @ dec_Wq   (4 K-segments of 96, reduced via LDS)
    {
      const int o = t & 127, seg = t >> 7;
      float acc = 0.0f;
      const float* wp = Wq + (size_t)(seg * 96) * 128 + o;
      for (int k = 0; k < 96; ++k) acc += cq[seg * 96 + k] * wp[(size_t)k * 128];
      part[seg][o] = acc;
    }
    __syncthreads();
    if (t < 128) qp[t] = (part[0][t] + part[1][t]) + (part[2][t] + part[3][t]);
    __syncthreads();
    // (3) per-head attention: wave w owns head h=w
    {
      const int h = w;
      float qreg[16];
#pragma unroll
      for (int d2 = 0; d2 < 16; ++d2) qreg[d2] = qp[h * 16 + d2];
      float sc[8];
#pragma unroll
      for (int j = 0; j < 8; ++j) {
        const int n = l + 64 * j;
        const float4* kr = reinterpret_cast<const float4*>(Kb + (size_t)n * 128 + h * 16);
        float4 A0 = kr[0], A1 = kr[1], A2 = kr[2], A3 = kr[3];
        float acc = qreg[0] * A0.x + qreg[1] * A0.y + qreg[2] * A0.z + qreg[3] * A0.w
                  + qreg[4] * A1.x + qreg[5] * A1.y + qreg[6] * A1.z + qreg[7] * A1.w
                  + qreg[8] * A2.x + qreg[9] * A2.y + qreg[10] * A2.z + qreg[11] * A2.w
                  + qreg[12] * A3.x + qreg[13] * A3.y + qreg[14] * A3.z + qreg[15] * A3.w;
        sc[j] = mask[n] ? NEGINF : acc * 0.25f;
      }
      float mh = sc[0];
#pragma unroll
      for (int j = 1; j < 8; ++j) mh = fmaxf(mh, sc[j]);
      for (int o = 32; o; o >>= 1) mh = fmaxf(mh, __shfl_xor(mh, o));
      float denom = 0.0f; float pe[8];
#pragma unroll
      for (int j = 0; j < 8; ++j) { pe[j] = expf(sc[j] - mh); denom += pe[j]; }
      for (int o = 32; o; o >>= 1) denom += __shfl_xor(denom, o);
#pragma unroll
      for (int j = 0; j < 8; ++j) p_lds[h][l + 64 * j] = pe[j];
      const float inv = 1.0f / denom;
      const int d = l & 15, g = l >> 4;           // n = 4*m2 + g avoids p_lds conflicts
      float acc = 0.0f;
      for (int m2 = 0; m2 < 128; ++m2) {
        const int n = (m2 << 2) | g;
        acc += p_lds[h][n] * Vb[(size_t)n * 128 + h * 16 + d];
      }
      acc += __shfl_xor(acc, 16);
      acc += __shfl_xor(acc, 32);
      if (l < 16) att[h * 16 + l] = acc * inv;
    }
    __syncthreads();
    // (4) qf = att @ dec_Wo
    {
      const int o = t & 127, seg = t >> 7;
      float acc = 0.0f;
      const float* wp = Wo + (size_t)(seg * 32) * 128 + o;
      for (int k = 0; k < 32; ++k) acc += att[seg * 32 + k] * wp[(size_t)k * 128];
      part[seg][o] = acc;
    }
    __syncthreads();
    if (t < 128) qf[t] = (part[0][t] + part[1][t]) + (part[2][t] + part[3][t]);
    __syncthreads();
    // (5) logits + gumbel, thread t = node n
    float lg, zv;
    {
      const int n = t;
      const float4* kr = reinterpret_cast<const float4*>(knb + (size_t)n * 128);
      float acc = 0.0f;
#pragma unroll 8
      for (int k = 0; k < 32; ++k) {
        float4 vv = kr[k];
        acc += qf[4 * k] * vv.x + qf[4 * k + 1] * vv.y
             + qf[4 * k + 2] * vv.z + qf[4 * k + 3] * vv.w;
      }
      const float lraw = acc / 11.313708498984761f;   // / sqrt(128), IEEE div
      lg = mask[n] ? NEGINF : tanhf(lraw) * 10.0f;
      l_lds[n] = lg;
      unsigned x0 = 0u, x1 = (unsigned)(b * 512 + n);
      const uint2 kk = keys[i];
      threefry2x32(kk.x, kk.y, x0, x1);
      const unsigned bits = x0 ^ x1;
      float f = __uint_as_float((bits >> 9) | 0x3f800000u) - 1.0f;
      f = f + TINYF;
      f = fmaxf(TINYF, f);
      zv = lg + (-logf(-logf(f)));
    }
    // (6) argmax(z) with first-index ties + max(logits)
    {
      float z = zv; int zi = t;
      for (int o = 32; o; o >>= 1) {
        float oz = __shfl_xor(z, o); int oi = __shfl_xor(zi, o);
        if (oz > z || (oz == z && oi < zi)) { z = oz; zi = oi; }
      }
      float mm = lg;
      for (int o = 32; o; o >>= 1) mm = fmaxf(mm, __shfl_xor(mm, o));
      if (l == 0) { redZ[w] = z; redI[w] = zi; redM[w] = mm; }
    }
    __syncthreads();
    if (t == 0) {
      float z = redZ[0]; int zi = redI[0]; float mm = redM[0];
      for (int ww = 1; ww < 8; ++ww) {
        if (redZ[ww] > z || (redZ[ww] == z && redI[ww] < zi)) { z = redZ[ww]; zi = redI[ww]; }
        mm = fmaxf(mm, redM[ww]);
      }
      action_s = zi; M_s = mm;
    }
    __syncthreads();
    {
      float e = expf(lg - M_s);
      for (int o = 32; o; o >>= 1) e += __shfl_xor(e, o);
      if (l == 0) redD[w] = e;
    }
    __syncthreads();
    const int a = action_s;
    if (t == 0) {
      const float ds = ((redD[0] + redD[1]) + (redD[2] + redD[3]))
                     + ((redD[4] + redD[5]) + (redD[6] + redD[7]));
      out_probs[i * 64 + b] = expf(l_lds[a] - M_s) / ds;
      out_act[i * 64 + b] = (float)a;
    }
    if (t < 128) {
      const float nl = X[(size_t)a * 128 + t];   // faithful bug: batch 0's rows
      lastv[t] = nl;
      if (i == 0) firstv[t] = nl;
    }
    if (t == 256) mask[a] = 1;
    __syncthreads();
  }
}

// ===========================================================================
extern "C" void kernel_launch(void* const* d_in, const int* in_sizes, int n_in,
                              void* d_out, int out_size, void* d_ws, size_t ws_size,
                              hipStream_t stream) {
  const float* problems = (const float*)d_in[0];
  const float* embed_W  = (const float*)d_in[1];
  const float* embed_b  = (const float*)d_in[2];
  const float* enc_Wq   = (const float*)d_in[3];
  const float* enc_Wk   = (const float*)d_in[4];
  const float* enc_Wv   = (const float*)d_in[5];
  const float* enc_Wo   = (const float*)d_in[6];
  const float* ln1g     = (const float*)d_in[7];
  const float* ln1b     = (const float*)d_in[8];
  const float* ffW1     = (const float*)d_in[9];
  const float* ffb1     = (const float*)d_in[10];
  const float* ffW2     = (const float*)d_in[11];
  const float* ffb2     = (const float*)d_in[12];
  const float* ln2g     = (const float*)d_in[13];
  const float* ln2b     = (const float*)d_in[14];
  const float* graph_W  = (const float*)d_in[15];
  const float* node_W   = (const float*)d_in[16];
  const float* dec_Wq   = (const float*)d_in[17];
  const float* dec_Wk   = (const float*)d_in[18];
  const float* dec_Wv   = (const float*)d_in[19];
  const float* dec_Wo   = (const float*)d_in[20];
  const float* W_v_f    = (const float*)d_in[21];
  const float* W_v_l    = (const float*)d_in[22];

  float* ws = (float*)d_ws;
  const size_t SZ = (size_t)64 * 512 * 128;      // 4194304 floats = 16 MB
  float* X  = ws;                                 // node states / node_context
  float* Y  = ws + SZ;                            // attn concat out / ffn out
  float* Q  = ws + 2 * SZ;                        // Q proj; later: pre-LN / K_dec
  float* K  = ws + 3 * SZ;                        // K proj; later: V_dec
  float* V  = ws + 4 * SZ;                        // V proj; later: k_node
  float* NM = ws + 5 * SZ;                        // node_mean [64,128]
  float* GC = NM + 64 * 128;                      // graph_context [64,128]

  float* out       = (float*)d_out;
  float* out_probs = out;                         // [512,64]
  float* out_act   = out + 512 * 64;              // [512,64] as float

  k_embed<<<16384, 256, 0, stream>>>(problems, embed_W, embed_b, X);

  for (int i = 0; i < 3; ++i) {
    const float* Wqi = enc_Wq + (size_t)i * 128 * 128;
    const float* Wki = enc_Wk + (size_t)i * 128 * 128;
    const float* Wvi = enc_Wv + (size_t)i * 128 * 128;
    const float* Woi = enc_Wo + (size_t)i * 128 * 128;
    k_gemm128<<<dim3(2048, 8), 256, 0, stream>>>(X, Wqi, nullptr, Q, 32768);
    k_gemm128<<<dim3(2048, 8), 256, 0, stream>>>(X, Wki, nullptr, K, 32768);
    k_gemm128<<<dim3(2048, 8), 256, 0, stream>>>(X, Wvi, nullptr, V, 32768);
    k_attn_enc<<<512, 256, 0, stream>>>(Q, K, V, Y);
    k_gemm128<<<dim3(2048, 8), 256, 0, stream>>>(Y, Woi, X, Q, 32768);  // +residual
    k_ln<<<8192, 256, 0, stream>>>(Q, ln1g + i * 128, ln1b + i * 128, X, 32768);
    k_ffn<<<4096, 256, 0, stream>>>(X, ffW1 + (size_t)i * 128 * 512, ffb1 + i * 512,
                                    ffW2 + (size_t)i * 512 * 128, ffb2 + i * 128, Y);
    k_ln<<<8192, 256, 0, stream>>>(Y, ln2g + i * 128, ln2b + i * 128, X, 32768);
  }

  // decoder precompute
  k_gemm128<<<dim3(2048, 8), 256, 0, stream>>>(X, dec_Wk, nullptr, Q, 32768); // K_dec
  k_gemm128<<<dim3(2048, 8), 256, 0, stream>>>(X, dec_Wv, nullptr, K, 32768); // V_dec
  k_gemm128<<<dim3(2048, 8), 256, 0, stream>>>(X, node_W, nullptr, V, 32768); // k_node
  k_mean<<<64, 128, 0, stream>>>(X, NM);
  k_gemm128<<<dim3(4, 8), 256, 0, stream>>>(NM, graph_W, nullptr, GC, 64);

  k_decoder<<<64, 512, 0, stream>>>(X, Q, K, V, GC, dec_Wq, dec_Wo,
                                    W_v_f, W_v_l, out_probs, out_act);
}

// Round 2
// 17616.530 us; speedup vs baseline: 2.0310x; 2.0310x over previous
//
#include <hip/hip_runtime.h>

// ============================================================================
// Transformer_72816875537065 v2: decoder restructured for latency.
//  - QL/QF/QG prefold of cq@Wq (batch-0 gather bug makes last/first rows of
//    node_context[0] -> precomputable for all 512 candidates)
//  - K_dec/V_dec/k_node stored transposed [b][c][n] for coalesced reads
//  - wave-per-head scores+softmax+PV with p kept in registers (no barriers)
//  - Wo in LDS; ~7 barriers/step
//  - encoder attention rewritten q-parallel (K in regs, V in LDS, score tiles)
// All fp32; threefry/gumbel/argmax identical to the R1 passing version.
// ============================================================================

#define NEGINF (-__builtin_huge_valf())
#define TINYF 1.17549435e-38f

__device__ __forceinline__ unsigned rotl32(unsigned v, int r) {
  return (v << r) | (v >> (32 - r));
}

__device__ __forceinline__ void threefry2x32(unsigned k0, unsigned k1,
                                             unsigned& x0, unsigned& x1) {
  unsigned k2 = k0 ^ k1 ^ 0x1BD11BDAu;
  x0 += k0; x1 += k1;
#define TF_R(r) { x0 += x1; x1 = rotl32(x1, (r)); x1 ^= x0; }
  TF_R(13) TF_R(15) TF_R(26) TF_R(6)
  x0 += k1; x1 += k2 + 1u;
  TF_R(17) TF_R(29) TF_R(16) TF_R(24)
  x0 += k2; x1 += k0 + 2u;
  TF_R(13) TF_R(15) TF_R(26) TF_R(6)
  x0 += k0; x1 += k1 + 3u;
  TF_R(17) TF_R(29) TF_R(16) TF_R(24)
  x0 += k1; x1 += k2 + 4u;
  TF_R(13) TF_R(15) TF_R(26) TF_R(6)
  x0 += k2; x1 += k0 + 5u;
#undef TF_R
}

// ---------------------------------------------------------------------------
__global__ __launch_bounds__(256) void k_embed(const float* __restrict__ P,
                                               const float* __restrict__ eW,
                                               const float* __restrict__ eb,
                                               float* __restrict__ X) {
  int idx = blockIdx.x * 256 + threadIdx.x;
  int row = idx >> 7, d = idx & 127;
  X[idx] = P[row * 2] * eW[d] + P[row * 2 + 1] * eW[128 + d] + eb[d];
}

// ---------------------------------------------------------------------------
// C[M,128] = A[M,128] @ W[128,128]  (+ residual R)
// ---------------------------------------------------------------------------
__global__ __launch_bounds__(256) void k_gemm128(const float* __restrict__ A,
                                                 const float* __restrict__ W,
                                                 const float* __restrict__ R,
                                                 float* __restrict__ C, int M) {
  __shared__ float As[16][129];
  __shared__ float Ws[128][17];
  const int tx = threadIdx.x & 15, ty = threadIdx.x >> 4;
  const int row0 = blockIdx.x * 16, col0 = blockIdx.y * 16;
  for (int idx = threadIdx.x; idx < 2048; idx += 256) {
    int r = idx >> 7, k = idx & 127;
    As[r][k] = (row0 + r < M) ? A[(size_t)(row0 + r) * 128 + k] : 0.0f;
    int kk = idx >> 4, c = idx & 15;
    Ws[kk][c] = W[(size_t)kk * 128 + col0 + c];
  }
  __syncthreads();
  float acc = 0.0f;
#pragma unroll 8
  for (int k = 0; k < 128; ++k) acc += As[ty][k] * Ws[k][tx];
  const int row = row0 + ty, col = col0 + tx;
  if (row < M) {
    if (R) acc += R[(size_t)row * 128 + col];
    C[(size_t)row * 128 + col] = acc;
  }
}

// ---------------------------------------------------------------------------
// Same GEMM but stores transposed per batch: CT[b][col][n], b=row>>9, n=row&511
// ---------------------------------------------------------------------------
__global__ __launch_bounds__(256) void k_gemm128t(const float* __restrict__ A,
                                                  const float* __restrict__ W,
                                                  float* __restrict__ CT, int M) {
  __shared__ float As[16][129];
  __shared__ float Ws[128][17];
  __shared__ float Ct[16][17];
  const int tx = threadIdx.x & 15, ty = threadIdx.x >> 4;
  const int row0 = blockIdx.x * 16, col0 = blockIdx.y * 16;
  for (int idx = threadIdx.x; idx < 2048; idx += 256) {
    int r = idx >> 7, k = idx & 127;
    As[r][k] = (row0 + r < M) ? A[(size_t)(row0 + r) * 128 + k] : 0.0f;
    int kk = idx >> 4, c = idx & 15;
    Ws[kk][c] = W[(size_t)kk * 128 + col0 + c];
  }
  __syncthreads();
  float acc = 0.0f;
#pragma unroll 8
  for (int k = 0; k < 128; ++k) acc += As[ty][k] * Ws[k][tx];
  Ct[ty][tx] = acc;
  __syncthreads();
  const int r2 = threadIdx.x & 15, c2 = threadIdx.x >> 4;
  const int row = row0 + r2, col = col0 + c2;
  if (row < M)
    CT[(size_t)(row >> 9) * 65536 + (size_t)col * 512 + (row & 511)] = Ct[r2][c2];
}

// ---------------------------------------------------------------------------
// Encoder attention v2: block = (b,h), 512 threads. K row t in registers,
// V staged in padded LDS, scores for 32-q tiles in LDS.
// ---------------------------------------------------------------------------
__global__ __launch_bounds__(512, 2) void k_attn_enc(const float* __restrict__ Q,
                                                     const float* __restrict__ K,
                                                     const float* __restrict__ V,
                                                     float* __restrict__ O) {
  const int b = blockIdx.x >> 3, h = blockIdx.x & 7;
  const int t = threadIdx.x, l = t & 63, w = t >> 6;
  __shared__ float4 Vs4[512][5];            // pad stride 5 float4 (20 floats)
  __shared__ float S[32][516];
  __shared__ float Qs[32][16];
  __shared__ float invr[32];
  const size_t base = (size_t)b * 512 * 128 + (size_t)h * 16;
  float4 k0, k1, k2, k3;
  {
    const float4* kr = reinterpret_cast<const float4*>(K + base + (size_t)t * 128);
    k0 = kr[0]; k1 = kr[1]; k2 = kr[2]; k3 = kr[3];
  }
  for (int idx = t; idx < 2048; idx += 512) {
    int n = idx >> 2, c = idx & 3;
    Vs4[n][c] = reinterpret_cast<const float4*>(V + base + (size_t)n * 128)[c];
  }
  __syncthreads();
  const float* vsf = reinterpret_cast<const float*>(Vs4);   // stride 20 per n
  for (int qt = 0; qt < 16; ++qt) {
    { int qr = t >> 4, d = t & 15;
      Qs[qr][d] = Q[base + (size_t)(qt * 32 + qr) * 128 + d]; }
    __syncthreads();
#pragma unroll 4
    for (int qi = 0; qi < 32; ++qi) {
      const float* qv = Qs[qi];
      float s = qv[0] * k0.x + qv[1] * k0.y + qv[2] * k0.z + qv[3] * k0.w
              + qv[4] * k1.x + qv[5] * k1.y + qv[6] * k1.z + qv[7] * k1.w
              + qv[8] * k2.x + qv[9] * k2.y + qv[10] * k2.z + qv[11] * k2.w
              + qv[12] * k3.x + qv[13] * k3.y + qv[14] * k3.z + qv[15] * k3.w;
      S[qi][t] = s * 0.25f;
    }
    __syncthreads();
    for (int r = 0; r < 4; ++r) {           // wave w owns rows 4w..4w+3
      const int qi = w * 4 + r;
      float m = S[qi][l];
      for (int j = 1; j < 8; ++j) m = fmaxf(m, S[qi][l + 64 * j]);
      for (int o = 32; o; o >>= 1) m = fmaxf(m, __shfl_xor(m, o));
      float sum = 0.0f;
      for (int j = 0; j < 8; ++j) {
        float e = expf(S[qi][l + 64 * j] - m);
        S[qi][l + 64 * j] = e;
        sum += e;
      }
      for (int o = 32; o; o >>= 1) sum += __shfl_xor(sum, o);
      if (l == 0) invr[qi] = 1.0f / sum;
    }
    __syncthreads();
    {
      const int qi = t >> 4, d = t & 15;
      float acc = 0.0f;
      for (int n = 0; n < 512; ++n) acc += S[qi][n] * vsf[n * 20 + d];
      O[base + (size_t)(qt * 32 + qi) * 128 + d] = acc * invr[qi];
    }
    // next tile's S/invr writes are fenced by the syncthreads above
  }
}

// ---------------------------------------------------------------------------
__global__ __launch_bounds__(256) void k_ln(const float* __restrict__ Y,
                                            const float* __restrict__ g,
                                            const float* __restrict__ bb,
                                            float* __restrict__ O, int M) {
  const int row = blockIdx.x * 4 + (threadIdx.x >> 6);
  const int l = threadIdx.x & 63;
  if (row >= M) return;
  const float* y = Y + (size_t)row * 128;
  float v0 = y[l], v1 = y[l + 64];
  float s = v0 + v1;
  for (int o = 32; o; o >>= 1) s += __shfl_xor(s, o);
  const float mu = s * (1.0f / 128.0f);
  float d0 = v0 - mu, d1 = v1 - mu;
  float q = d0 * d0 + d1 * d1;
  for (int o = 32; o; o >>= 1) q += __shfl_xor(q, o);
  const float sd = sqrtf(q * (1.0f / 128.0f) + 1e-6f);
  O[(size_t)row * 128 + l]      = d0 / sd * g[l] + bb[l];
  O[(size_t)row * 128 + l + 64] = d1 / sd * g[l + 64] + bb[l + 64];
}

// ---------------------------------------------------------------------------
__global__ __launch_bounds__(256) void k_ffn(const float* __restrict__ X,
                                             const float* __restrict__ W1,
                                             const float* __restrict__ b1,
                                             const float* __restrict__ W2,
                                             const float* __restrict__ b2,
                                             float* __restrict__ Y) {
  __shared__ float xr[8][129];
  __shared__ float hbuf[8][513];
  const int t = threadIdx.x;
  const size_t row0 = (size_t)blockIdx.x * 8;
  for (int idx = t; idx < 1024; idx += 256) {
    int r = idx >> 7, d = idx & 127;
    xr[r][d] = X[(row0 + r) * 128 + d];
  }
  __syncthreads();
  for (int j = t; j < 512; j += 256) {
    float acc[8] = {0, 0, 0, 0, 0, 0, 0, 0};
    const float* wp = W1 + j;
    for (int k = 0; k < 128; ++k) {
      float wv = wp[(size_t)k * 512];
#pragma unroll
      for (int r = 0; r < 8; ++r) acc[r] += xr[r][k] * wv;
    }
    float bj = b1[j];
#pragma unroll
    for (int r = 0; r < 8; ++r) hbuf[r][j] = fmaxf(acc[r] + bj, 0.0f);
  }
  __syncthreads();
  {
    const int o = t & 127, r0 = t >> 7;
    float acc[4] = {0, 0, 0, 0};
    const float* wp = W2 + o;
    for (int k = 0; k < 512; ++k) {
      float wv = wp[(size_t)k * 128];
#pragma unroll
      for (int u = 0; u < 4; ++u) acc[u] += hbuf[r0 + 2 * u][k] * wv;
    }
    float bo = b2[o];
#pragma unroll
    for (int u = 0; u < 4; ++u) {
      int r = r0 + 2 * u;
      Y[(row0 + r) * 128 + o] = acc[u] + bo + xr[r][o];
    }
  }
}

// ---------------------------------------------------------------------------
__global__ __launch_bounds__(128) void k_mean(const float* __restrict__ X,
                                              float* __restrict__ NM) {
  const int b = blockIdx.x, d = threadIdx.x;
  float s = 0.0f;
  for (int n = 0; n < 512; ++n) s += X[((size_t)b * 512 + n) * 128 + d];
  NM[b * 128 + d] = s * (1.0f / 512.0f);
}

// ---------------------------------------------------------------------------
// Decoder v2: 1 block/batch, 512 threads, wave w = head w.
// Kt/Vt/knT are [b][c][n] transposed; QG/QL/QF prefolded query pieces.
// ---------------------------------------------------------------------------
__global__ __launch_bounds__(512, 2) void k_decoder(
    const float* __restrict__ Kt, const float* __restrict__ Vt,
    const float* __restrict__ knT,
    const float* __restrict__ QG, const float* __restrict__ QL,
    const float* __restrict__ QF, const float* __restrict__ QL0,
    const float* __restrict__ QF0, const float* __restrict__ Wo,
    float* __restrict__ out_probs, float* __restrict__ out_act) {
  const int b = blockIdx.x, t = threadIdx.x;
  const int l = t & 63, w = t >> 6;

  __shared__ float Wo_s[128 * 128];
  __shared__ float att[128], qf[128];
  __shared__ float part[4][128];
  __shared__ float l_lds[512];
  __shared__ unsigned char mask[512];
  __shared__ uint2 keys[512];
  __shared__ float redZ[8]; __shared__ int redI[8];
  __shared__ float redM[8]; __shared__ float redD[8];
  __shared__ int action_s; __shared__ float M_s;
  __shared__ int ap_s, af_s;

  for (int idx = t; idx < 16384; idx += 512) Wo_s[idx] = Wo[idx];
  {
    unsigned x0 = 0u, x1 = (unsigned)t;
    threefry2x32(0u, 42u, x0, x1);
    keys[t] = make_uint2(x0, x1);
    mask[t] = 0;
  }
  if (t == 0) { ap_s = 0; af_s = 0; }
  __syncthreads();

  const float4* KtB = reinterpret_cast<const float4*>(Kt + (size_t)b * 65536);
  const float4* VtB = reinterpret_cast<const float4*>(Vt + (size_t)b * 65536);
  const float*  knB = knT + (size_t)b * 65536;
  const uchar4* m4  = reinterpret_cast<const uchar4*>(mask);

  for (int i = 0; i < 512; ++i) {
    const int h = w;
    // ---- (A) query for this head: QG + QL[ap] + QF[af] (no barrier needed)
    float qval = 0.0f;
    if (l < 16) {
      const int c = h * 16 + l;
      float s_ = QG[b * 128 + c];
      s_ += (i == 0) ? QL0[c] : QL[(size_t)ap_s * 128 + c];
      s_ += (i == 0) ? QF0[c] : QF[(size_t)af_s * 128 + c];
      qval = s_;
    }
    float q[16];
#pragma unroll
    for (int d = 0; d < 16; ++d) q[d] = __shfl(qval, d);
    // ---- (B) scores: lane l covers n = 4l..4l+3 and 256+4l..256+4l+3
    float4 a0 = {0, 0, 0, 0}, a1 = {0, 0, 0, 0};
#pragma unroll
    for (int d = 0; d < 16; ++d) {
      const float4 ka = KtB[(h * 16 + d) * 128 + l];
      const float4 kb = KtB[(h * 16 + d) * 128 + 64 + l];
      a0.x += q[d] * ka.x; a0.y += q[d] * ka.y; a0.z += q[d] * ka.z; a0.w += q[d] * ka.w;
      a1.x += q[d] * kb.x; a1.y += q[d] * kb.y; a1.z += q[d] * kb.z; a1.w += q[d] * kb.w;
    }
    const uchar4 ma = m4[l], mb = m4[64 + l];
    float4 s0, s1;
    s0.x = ma.x ? NEGINF : a0.x * 0.25f;  s0.y = ma.y ? NEGINF : a0.y * 0.25f;
    s0.z = ma.z ? NEGINF : a0.z * 0.25f;  s0.w = ma.w ? NEGINF : a0.w * 0.25f;
    s1.x = mb.x ? NEGINF : a1.x * 0.25f;  s1.y = mb.y ? NEGINF : a1.y * 0.25f;
    s1.z = mb.z ? NEGINF : a1.z * 0.25f;  s1.w = mb.w ? NEGINF : a1.w * 0.25f;
    float mh = fmaxf(fmaxf(fmaxf(s0.x, s0.y), fmaxf(s0.z, s0.w)),
                     fmaxf(fmaxf(s1.x, s1.y), fmaxf(s1.z, s1.w)));
    for (int o = 32; o; o >>= 1) mh = fmaxf(mh, __shfl_xor(mh, o));
    float4 e0, e1;
    e0.x = expf(s0.x - mh); e0.y = expf(s0.y - mh);
    e0.z = expf(s0.z - mh); e0.w = expf(s0.w - mh);
    e1.x = expf(s1.x - mh); e1.y = expf(s1.y - mh);
    e1.z = expf(s1.z - mh); e1.w = expf(s1.w - mh);
    float den = ((e0.x + e0.y) + (e0.z + e0.w)) + ((e1.x + e1.y) + (e1.z + e1.w));
    for (int o = 32; o; o >>= 1) den += __shfl_xor(den, o);
    const float inv = 1.0f / den;
    // ---- (C) PV: p stays in registers (lane l's e0/e1 are exactly its n's)
    float attv = 0.0f;
#pragma unroll
    for (int d = 0; d < 16; ++d) {
      const float4 va = VtB[(h * 16 + d) * 128 + l];
      const float4 vb = VtB[(h * 16 + d) * 128 + 64 + l];
      float ps = e0.x * va.x + e0.y * va.y + e0.z * va.z + e0.w * va.w
               + e1.x * vb.x + e1.y * vb.y + e1.z * vb.z + e1.w * vb.w;
      for (int o = 1; o < 64; o <<= 1) ps += __shfl_xor(ps, o);
      if (l == d) attv = ps * inv;
    }
    if (l < 16) att[h * 16 + l] = attv;
    __syncthreads();                                   // 1
    // ---- (D) qf = att @ Wo (Wo in LDS)
    {
      const int o = t & 127, seg = t >> 7;
      float acc = 0.0f;
      for (int k = 0; k < 32; ++k)
        acc += att[seg * 32 + k] * Wo_s[(seg * 32 + k) * 128 + o];
      part[seg][o] = acc;
    }
    __syncthreads();                                   // 2
    if (t < 128) qf[t] = (part[0][t] + part[1][t]) + (part[2][t] + part[3][t]);
    __syncthreads();                                   // 3
    // ---- (E) logits + gumbel, thread t = node n (knT coalesced over n)
    float lg, zv;
    {
      float acc = 0.0f;
      const float* kc = knB + t;
      for (int k = 0; k < 128; ++k) acc += qf[k] * kc[(size_t)k * 512];
      const float lraw = acc / 11.313708498984761f;    // / sqrt(128)
      lg = mask[t] ? NEGINF : tanhf(lraw) * 10.0f;
      l_lds[t] = lg;
      unsigned x0 = 0u, x1 = (unsigned)(b * 512 + t);
      const uint2 kk = keys[i];
      threefry2x32(kk.x, kk.y, x0, x1);
      const unsigned bits = x0 ^ x1;
      float f = __uint_as_float((bits >> 9) | 0x3f800000u) - 1.0f;
      f = f + TINYF;
      f = fmaxf(TINYF, f);
      zv = lg + (-logf(-logf(f)));
    }
    // ---- argmax + softmax bookkeeping (identical to R1)
    {
      float z = zv; int zi = t;
      for (int o = 32; o; o >>= 1) {
        float oz = __shfl_xor(z, o); int oi = __shfl_xor(zi, o);
        if (oz > z || (oz == z && oi < zi)) { z = oz; zi = oi; }
      }
      float mm = lg;
      for (int o = 32; o; o >>= 1) mm = fmaxf(mm, __shfl_xor(mm, o));
      if (l == 0) { redZ[w] = z; redI[w] = zi; redM[w] = mm; }
    }
    __syncthreads();                                   // 4
    if (t == 0) {
      float z = redZ[0]; int zi = redI[0]; float mm = redM[0];
      for (int ww = 1; ww < 8; ++ww) {
        if (redZ[ww] > z || (redZ[ww] == z && redI[ww] < zi)) { z = redZ[ww]; zi = redI[ww]; }
        mm = fmaxf(mm, redM[ww]);
      }
      action_s = zi; M_s = mm;
    }
    __syncthreads();                                   // 5
    {
      float e = expf(lg - M_s);
      for (int o = 32; o; o >>= 1) e += __shfl_xor(e, o);
      if (l == 0) redD[w] = e;
    }
    __syncthreads();                                   // 6
    if (t == 0) {
      const int a = action_s;
      const float ds = ((redD[0] + redD[1]) + (redD[2] + redD[3]))
                     + ((redD[4] + redD[5]) + (redD[6] + redD[7]));
      out_probs[i * 64 + b] = expf(l_lds[a] - M_s) / ds;
      out_act[i * 64 + b] = (float)a;
      ap_s = a;
      if (i == 0) af_s = a;
      mask[a] = 1;
    }
    __syncthreads();                                   // 7
  }
}

// ===========================================================================
extern "C" void kernel_launch(void* const* d_in, const int* in_sizes, int n_in,
                              void* d_out, int out_size, void* d_ws, size_t ws_size,
                              hipStream_t stream) {
  const float* problems = (const float*)d_in[0];
  const float* embed_W  = (const float*)d_in[1];
  const float* embed_b  = (const float*)d_in[2];
  const float* enc_Wq   = (const float*)d_in[3];
  const float* enc_Wk   = (const float*)d_in[4];
  const float* enc_Wv   = (const float*)d_in[5];
  const float* enc_Wo   = (const float*)d_in[6];
  const float* ln1g     = (const float*)d_in[7];
  const float* ln1b     = (const float*)d_in[8];
  const float* ffW1     = (const float*)d_in[9];
  const float* ffb1     = (const float*)d_in[10];
  const float* ffW2     = (const float*)d_in[11];
  const float* ffb2     = (const float*)d_in[12];
  const float* ln2g     = (const float*)d_in[13];
  const float* ln2b     = (const float*)d_in[14];
  const float* graph_W  = (const float*)d_in[15];
  const float* node_W   = (const float*)d_in[16];
  const float* dec_Wq   = (const float*)d_in[17];
  const float* dec_Wk   = (const float*)d_in[18];
  const float* dec_Wv   = (const float*)d_in[19];
  const float* dec_Wo   = (const float*)d_in[20];
  const float* W_v_f    = (const float*)d_in[21];
  const float* W_v_l    = (const float*)d_in[22];

  float* ws = (float*)d_ws;
  const size_t SZ = (size_t)64 * 512 * 128;      // 16 MB each
  float* X  = ws;                                 // node states / node_context
  float* Y  = ws + SZ;                            // attn/ffn tmp; later Q-prefolds
  float* Qb = ws + 2 * SZ;                        // Q proj; later Kt
  float* Kb = ws + 3 * SZ;                        // K proj; later Vt
  float* Vb = ws + 4 * SZ;                        // V proj; later knT
  float* NM = ws + 5 * SZ;                        // [64,128]
  float* GC = NM + 64 * 128;                      // [64,128]

  // Q-prefold buffers live in Y (free after encoder)
  float* QG  = Y;                                 // [64,128]
  float* QL  = Y + 8192;                          // [512,128]
  float* QF  = Y + 8192 + 65536;                  // [512,128]
  float* QL0 = Y + 8192 + 131072;                 // [128]
  float* QF0 = QL0 + 128;                         // [128]

  float* out       = (float*)d_out;
  float* out_probs = out;                         // [512,64]
  float* out_act   = out + 512 * 64;              // [512,64] as float

  k_embed<<<16384, 256, 0, stream>>>(problems, embed_W, embed_b, X);

  for (int i = 0; i < 3; ++i) {
    const float* Wqi = enc_Wq + (size_t)i * 128 * 128;
    const float* Wki = enc_Wk + (size_t)i * 128 * 128;
    const float* Wvi = enc_Wv + (size_t)i * 128 * 128;
    const float* Woi = enc_Wo + (size_t)i * 128 * 128;
    k_gemm128<<<dim3(2048, 8), 256, 0, stream>>>(X, Wqi, nullptr, Qb, 32768);
    k_gemm128<<<dim3(2048, 8), 256, 0, stream>>>(X, Wki, nullptr, Kb, 32768);
    k_gemm128<<<dim3(2048, 8), 256, 0, stream>>>(X, Wvi, nullptr, Vb, 32768);
    k_attn_enc<<<512, 512, 0, stream>>>(Qb, Kb, Vb, Y);
    k_gemm128<<<dim3(2048, 8), 256, 0, stream>>>(Y, Woi, X, Qb, 32768);  // +resid
    k_ln<<<8192, 256, 0, stream>>>(Qb, ln1g + i * 128, ln1b + i * 128, X, 32768);
    k_ffn<<<4096, 256, 0, stream>>>(X, ffW1 + (size_t)i * 128 * 512, ffb1 + i * 512,
                                    ffW2 + (size_t)i * 512 * 128, ffb2 + i * 128, Y);
    k_ln<<<8192, 256, 0, stream>>>(Y, ln2g + i * 128, ln2b + i * 128, X, 32768);
  }

  // decoder precompute: transposed projections + query prefolds
  k_gemm128t<<<dim3(2048, 8), 256, 0, stream>>>(X, dec_Wk, Qb, 32768);  // Kt
  k_gemm128t<<<dim3(2048, 8), 256, 0, stream>>>(X, dec_Wv, Kb, 32768);  // Vt
  k_gemm128t<<<dim3(2048, 8), 256, 0, stream>>>(X, node_W, Vb, 32768);  // knT
  k_mean<<<64, 128, 0, stream>>>(X, NM);
  k_gemm128<<<dim3(4, 8), 256, 0, stream>>>(NM, graph_W, nullptr, GC, 64);
  k_gemm128<<<dim3(4, 8), 256, 0, stream>>>(GC, dec_Wq, nullptr, QG, 64);
  k_gemm128<<<dim3(32, 8), 256, 0, stream>>>(X, dec_Wq + 16384, nullptr, QL, 512);
  k_gemm128<<<dim3(32, 8), 256, 0, stream>>>(X, dec_Wq + 32768, nullptr, QF, 512);
  k_gemm128<<<dim3(1, 8), 256, 0, stream>>>(W_v_l, dec_Wq + 16384, nullptr, QL0, 1);
  k_gemm128<<<dim3(1, 8), 256, 0, stream>>>(W_v_f, dec_Wq + 32768, nullptr, QF0, 1);

  k_decoder<<<64, 512, 0, stream>>>(Qb, Kb, Vb, QG, QL, QF, QL0, QF0, dec_Wo,
                                    out_probs, out_act);
}

// Round 3
// 9547.891 us; speedup vs baseline: 3.7473x; 1.8451x over previous
//
#include <hip/hip_runtime.h>

// ============================================================================
// Transformer_72816875537065 v3:
//  - decoder: Wo folded into precomputed KnW^T; K-slice in registers; PV via
//    per-wave LDS reduce; 2 barriers/step; register masks; unrolled GEMV.
//  - encoder: 64x64-tile fp32 GEMM (k_gemm64) with fused epilogues replaces
//    16x16 GEMM + k_ffn (hidden split into two 256-halves via workspace).
// All fp32; threefry/gumbel/argmax byte-identical to the passing R1/R2 code.
// ============================================================================

#define NEGINF (-__builtin_huge_valf())
#define TINYF 1.17549435e-38f

__device__ __forceinline__ unsigned rotl32(unsigned v, int r) {
  return (v << r) | (v >> (32 - r));
}

__device__ __forceinline__ void threefry2x32(unsigned k0, unsigned k1,
                                             unsigned& x0, unsigned& x1) {
  unsigned k2 = k0 ^ k1 ^ 0x1BD11BDAu;
  x0 += k0; x1 += k1;
#define TF_R(r) { x0 += x1; x1 = rotl32(x1, (r)); x1 ^= x0; }
  TF_R(13) TF_R(15) TF_R(26) TF_R(6)
  x0 += k1; x1 += k2 + 1u;
  TF_R(17) TF_R(29) TF_R(16) TF_R(24)
  x0 += k2; x1 += k0 + 2u;
  TF_R(13) TF_R(15) TF_R(26) TF_R(6)
  x0 += k0; x1 += k1 + 3u;
  TF_R(17) TF_R(29) TF_R(16) TF_R(24)
  x0 += k1; x1 += k2 + 4u;
  TF_R(13) TF_R(15) TF_R(26) TF_R(6)
  x0 += k2; x1 += k0 + 5u;
#undef TF_R
}

__device__ __forceinline__ float4 f4fma(float s, float4 v, float4 a) {
  a.x += s * v.x; a.y += s * v.y; a.z += s * v.z; a.w += s * v.w; return a;
}

// ---------------------------------------------------------------------------
__global__ __launch_bounds__(256) void k_embed(const float* __restrict__ P,
                                               const float* __restrict__ eW,
                                               const float* __restrict__ eb,
                                               float* __restrict__ X) {
  int idx = blockIdx.x * 256 + threadIdx.x;
  int row = idx >> 7, d = idx & 127;
  X[idx] = P[row * 2] * eW[d] + P[row * 2 + 1] * eW[128 + d] + eb[d];
}

// ---------------------------------------------------------------------------
// Small-M GEMM (M=64/1): C[M,128] = A[M,128] @ W[128,128]
// ---------------------------------------------------------------------------
__global__ __launch_bounds__(256) void k_gemm128(const float* __restrict__ A,
                                                 const float* __restrict__ W,
                                                 const float* __restrict__ R,
                                                 float* __restrict__ C, int M) {
  __shared__ float As[16][129];
  __shared__ float Ws[128][17];
  const int tx = threadIdx.x & 15, ty = threadIdx.x >> 4;
  const int row0 = blockIdx.x * 16, col0 = blockIdx.y * 16;
  for (int idx = threadIdx.x; idx < 2048; idx += 256) {
    int r = idx >> 7, k = idx & 127;
    As[r][k] = (row0 + r < M) ? A[(size_t)(row0 + r) * 128 + k] : 0.0f;
    int kk = idx >> 4, c = idx & 15;
    Ws[kk][c] = W[(size_t)kk * 128 + col0 + c];
  }
  __syncthreads();
  float acc = 0.0f;
#pragma unroll 8
  for (int k = 0; k < 128; ++k) acc += As[ty][k] * Ws[k][tx];
  const int row = row0 + ty, col = col0 + tx;
  if (row < M) {
    if (R) acc += R[(size_t)row * 128 + col];
    C[(size_t)row * 128 + col] = acc;
  }
}

// ---------------------------------------------------------------------------
// 64x64-tile fp32 GEMM, 256 threads, 4x4 outputs/thread, K in 128-chunks.
// flags: bias | relu | addR | accumC | T-store | W-transposed
// T-store: C treated as per-batch transposed CT[b][col][n] (batch = row>>9).
// ---------------------------------------------------------------------------
#define GEP_BIAS 1
#define GEP_RELU 2
#define GEP_ADDR 4
#define GEP_ACC  8
#define GEP_TST  16
#define GEP_WT   32

__global__ __launch_bounds__(256, 2) void k_gemm64(
    const float* __restrict__ A, int lda,
    const float* __restrict__ W, int ldw,
    const float* __restrict__ bias,
    const float* __restrict__ R,
    float* __restrict__ C, int ldc,
    int K, int flags) {
  __shared__ float AsT[128 * 68];
  __shared__ float Bs[128 * 68];
  const int t = threadIdx.x;
  const int tx = t & 15, ty = t >> 4;
  const int row0 = blockIdx.x * 64, col0 = blockIdx.y * 64;
  float4 acc[4];
  acc[0] = acc[1] = acc[2] = acc[3] = make_float4(0.f, 0.f, 0.f, 0.f);

  for (int K0 = 0; K0 < K; K0 += 128) {
    if (K0) __syncthreads();
    // stage A -> AsT[k][r]
#pragma unroll
    for (int j = 0; j < 8; ++j) {
      int idx = t + j * 256;
      int r = idx & 63, kq = idx >> 6;
      float4 v = *(const float4*)&A[(size_t)(row0 + r) * lda + K0 + kq * 4];
      AsT[(kq * 4 + 0) * 68 + r] = v.x;
      AsT[(kq * 4 + 1) * 68 + r] = v.y;
      AsT[(kq * 4 + 2) * 68 + r] = v.z;
      AsT[(kq * 4 + 3) * 68 + r] = v.w;
    }
    // stage B -> Bs[k][c]
    if (flags & GEP_WT) {
#pragma unroll
      for (int j = 0; j < 8; ++j) {
        int idx = t + j * 256;
        int cc = idx & 63, kq = idx >> 6;
        float4 v = *(const float4*)&W[(size_t)(col0 + cc) * ldw + K0 + kq * 4];
        Bs[(kq * 4 + 0) * 68 + cc] = v.x;
        Bs[(kq * 4 + 1) * 68 + cc] = v.y;
        Bs[(kq * 4 + 2) * 68 + cc] = v.z;
        Bs[(kq * 4 + 3) * 68 + cc] = v.w;
      }
    } else {
#pragma unroll
      for (int j = 0; j < 8; ++j) {
        int idx = t + j * 256;
        int c4 = idx & 15, k = idx >> 4;
        *(float4*)&Bs[k * 68 + c4 * 4] =
            *(const float4*)&W[(size_t)(K0 + k) * ldw + col0 + c4 * 4];
      }
    }
    __syncthreads();
#pragma unroll 8
    for (int k = 0; k < 128; ++k) {
      float4 av = *(const float4*)&AsT[k * 68 + ty * 4];
      float4 bv = *(const float4*)&Bs[k * 68 + tx * 4];
      acc[0] = f4fma(av.x, bv, acc[0]);
      acc[1] = f4fma(av.y, bv, acc[1]);
      acc[2] = f4fma(av.z, bv, acc[2]);
      acc[3] = f4fma(av.w, bv, acc[3]);
    }
  }

  if (flags & GEP_TST) {
    __syncthreads();
    float* CtT = AsT;   // reuse (64 x 68)
#pragma unroll
    for (int i2 = 0; i2 < 4; ++i2) {
      CtT[(tx * 4 + 0) * 68 + ty * 4 + i2] = ((const float*)&acc[i2])[0];
      CtT[(tx * 4 + 1) * 68 + ty * 4 + i2] = ((const float*)&acc[i2])[1];
      CtT[(tx * 4 + 2) * 68 + ty * 4 + i2] = ((const float*)&acc[i2])[2];
      CtT[(tx * 4 + 3) * 68 + ty * 4 + i2] = ((const float*)&acc[i2])[3];
    }
    __syncthreads();
    for (int j = 0; j < 16; ++j) {
      int idx = t + j * 256;                 // 0..4095
      int n = idx & 63, c = idx >> 6;
      int grow = row0 + n;
      C[(size_t)(grow >> 9) * 65536 + (size_t)(col0 + c) * 512 + (grow & 511)] =
          CtT[c * 68 + n];
    }
  } else {
#pragma unroll
    for (int i2 = 0; i2 < 4; ++i2) {
      const int row = row0 + ty * 4 + i2, col = col0 + tx * 4;
      float4 v = acc[i2];
      if (flags & GEP_BIAS) {
        float4 b4 = *(const float4*)&bias[col];
        v.x += b4.x; v.y += b4.y; v.z += b4.z; v.w += b4.w;
      }
      if (flags & GEP_RELU) {
        v.x = fmaxf(v.x, 0.f); v.y = fmaxf(v.y, 0.f);
        v.z = fmaxf(v.z, 0.f); v.w = fmaxf(v.w, 0.f);
      }
      if (flags & GEP_ADDR) {
        float4 r4 = *(const float4*)&R[(size_t)row * ldc + col];
        v.x += r4.x; v.y += r4.y; v.z += r4.z; v.w += r4.w;
      }
      if (flags & GEP_ACC) {
        float4 c4 = *(const float4*)&C[(size_t)row * ldc + col];
        v.x += c4.x; v.y += c4.y; v.z += c4.z; v.w += c4.w;
      }
      *(float4*)&C[(size_t)row * ldc + col] = v;
    }
  }
}

// ---------------------------------------------------------------------------
// Encoder attention: block = (b,h), 512 threads. K row t in regs, V in LDS.
// ---------------------------------------------------------------------------
__global__ __launch_bounds__(512, 2) void k_attn_enc(const float* __restrict__ Q,
                                                     const float* __restrict__ K,
                                                     const float* __restrict__ V,
                                                     float* __restrict__ O) {
  const int b = blockIdx.x >> 3, h = blockIdx.x & 7;
  const int t = threadIdx.x, l = t & 63, w = t >> 6;
  __shared__ float4 Vs4[512][5];
  __shared__ float S[32][516];
  __shared__ float Qs[32][16];
  __shared__ float invr[32];
  const size_t base = (size_t)b * 512 * 128 + (size_t)h * 16;
  float4 k0, k1, k2, k3;
  {
    const float4* kr = reinterpret_cast<const float4*>(K + base + (size_t)t * 128);
    k0 = kr[0]; k1 = kr[1]; k2 = kr[2]; k3 = kr[3];
  }
  for (int idx = t; idx < 2048; idx += 512) {
    int n = idx >> 2, c = idx & 3;
    Vs4[n][c] = reinterpret_cast<const float4*>(V + base + (size_t)n * 128)[c];
  }
  __syncthreads();
  const float* vsf = reinterpret_cast<const float*>(Vs4);
  for (int qt = 0; qt < 16; ++qt) {
    { int qr = t >> 4, d = t & 15;
      Qs[qr][d] = Q[base + (size_t)(qt * 32 + qr) * 128 + d]; }
    __syncthreads();
#pragma unroll 4
    for (int qi = 0; qi < 32; ++qi) {
      const float* qv = Qs[qi];
      float s = qv[0] * k0.x + qv[1] * k0.y + qv[2] * k0.z + qv[3] * k0.w
              + qv[4] * k1.x + qv[5] * k1.y + qv[6] * k1.z + qv[7] * k1.w
              + qv[8] * k2.x + qv[9] * k2.y + qv[10] * k2.z + qv[11] * k2.w
              + qv[12] * k3.x + qv[13] * k3.y + qv[14] * k3.z + qv[15] * k3.w;
      S[qi][t] = s * 0.25f;
    }
    __syncthreads();
    for (int r = 0; r < 4; ++r) {
      const int qi = w * 4 + r;
      float m = S[qi][l];
      for (int j = 1; j < 8; ++j) m = fmaxf(m, S[qi][l + 64 * j]);
      for (int o = 32; o; o >>= 1) m = fmaxf(m, __shfl_xor(m, o));
      float sum = 0.0f;
      for (int j = 0; j < 8; ++j) {
        float e = expf(S[qi][l + 64 * j] - m);
        S[qi][l + 64 * j] = e;
        sum += e;
      }
      for (int o = 32; o; o >>= 1) sum += __shfl_xor(sum, o);
      if (l == 0) invr[qi] = 1.0f / sum;
    }
    __syncthreads();
    {
      const int qi = t >> 4, d = t & 15;
      float acc = 0.0f;
      for (int n = 0; n < 512; ++n) acc += S[qi][n] * vsf[n * 20 + d];
      O[base + (size_t)(qt * 32 + qi) * 128 + d] = acc * invr[qi];
    }
  }
}

// ---------------------------------------------------------------------------
__global__ __launch_bounds__(256) void k_ln(const float* __restrict__ Y,
                                            const float* __restrict__ g,
                                            const float* __restrict__ bb,
                                            float* __restrict__ O, int M) {
  const int row = blockIdx.x * 4 + (threadIdx.x >> 6);
  const int l = threadIdx.x & 63;
  if (row >= M) return;
  const float* y = Y + (size_t)row * 128;
  float v0 = y[l], v1 = y[l + 64];
  float s = v0 + v1;
  for (int o = 32; o; o >>= 1) s += __shfl_xor(s, o);
  const float mu = s * (1.0f / 128.0f);
  float d0 = v0 - mu, d1 = v1 - mu;
  float q = d0 * d0 + d1 * d1;
  for (int o = 32; o; o >>= 1) q += __shfl_xor(q, o);
  const float sd = sqrtf(q * (1.0f / 128.0f) + 1e-6f);
  O[(size_t)row * 128 + l]      = d0 / sd * g[l] + bb[l];
  O[(size_t)row * 128 + l + 64] = d1 / sd * g[l + 64] + bb[l + 64];
}

// ---------------------------------------------------------------------------
__global__ __launch_bounds__(128) void k_mean(const float* __restrict__ X,
                                              float* __restrict__ NM) {
  const int b = blockIdx.x, d = threadIdx.x;
  float s = 0.0f;
  for (int n = 0; n < 512; ++n) s += X[((size_t)b * 512 + n) * 128 + d];
  NM[b * 128 + d] = s * (1.0f / 512.0f);
}

// ---------------------------------------------------------------------------
// Decoder v3: 1 block/batch, 512 threads, wave w = head w.
// Kt in registers; Vt [b][c][n]; KnWT [b][k][n] (Wo pre-folded into kn).
// 2 barriers/step; masks in registers; all threads derive the argmax.
// ---------------------------------------------------------------------------
__global__ __launch_bounds__(512, 2) void k_decoder(
    const float* __restrict__ Kt, const float* __restrict__ Vt,
    const float* __restrict__ KnWT,
    const float* __restrict__ QG, const float* __restrict__ QL,
    const float* __restrict__ QF, const float* __restrict__ QL0,
    const float* __restrict__ QF0,
    float* __restrict__ out_probs, float* __restrict__ out_act) {
  const int b = blockIdx.x, t = threadIdx.x;
  const int l = t & 63, w = t >> 6, h = w;

  __shared__ float att_s[128];
  __shared__ float pv[8][64 * 17];
  __shared__ float l_lds[512];
  __shared__ uint2 keys[512];
  __shared__ float redZ[8]; __shared__ int redI[8];
  __shared__ float redM[8]; __shared__ float redD[8];

  {
    unsigned x0 = 0u, x1 = (unsigned)t;
    threefry2x32(0u, 42u, x0, x1);
    keys[t] = make_uint2(x0, x1);
  }
  __syncthreads();

  const float4* KtB = reinterpret_cast<const float4*>(Kt + (size_t)b * 65536);
  const float4* VtB = reinterpret_cast<const float4*>(Vt + (size_t)b * 65536);
  const float*  knB = KnWT + (size_t)b * 65536;

  // K head-slice resident in registers: 32 float4 = 128 VGPRs
  float4 ka[16], kb[16];
#pragma unroll
  for (int d = 0; d < 16; ++d) {
    ka[d] = KtB[(h * 16 + d) * 128 + l];
    kb[d] = KtB[(h * 16 + d) * 128 + 64 + l];
  }

  // additive masks in registers (0 or -inf)
  float4 mk0 = make_float4(0.f, 0.f, 0.f, 0.f);
  float4 mk1 = make_float4(0.f, 0.f, 0.f, 0.f);
  float emask = 0.0f;
  int ap = 0, af = 0;

  for (int i = 0; i < 512; ++i) {
    // ---- (A) q for this head
    float qval = 0.0f;
    if (l < 16) {
      const int c = h * 16 + l;
      float s_ = QG[b * 128 + c];
      s_ += (i == 0) ? QL0[c] : QL[(size_t)ap * 128 + c];
      s_ += (i == 0) ? QF0[c] : QF[(size_t)af * 128 + c];
      qval = s_;
    }
    float q[16];
#pragma unroll
    for (int d = 0; d < 16; ++d) q[d] = __shfl(qval, d);
    // ---- (B) scores from register K
    float4 a0 = make_float4(0.f, 0.f, 0.f, 0.f);
    float4 a1 = make_float4(0.f, 0.f, 0.f, 0.f);
#pragma unroll
    for (int d = 0; d < 16; ++d) {
      a0 = f4fma(q[d], ka[d], a0);
      a1 = f4fma(q[d], kb[d], a1);
    }
    float4 s0, s1;
    s0.x = a0.x * 0.25f + mk0.x;  s0.y = a0.y * 0.25f + mk0.y;
    s0.z = a0.z * 0.25f + mk0.z;  s0.w = a0.w * 0.25f + mk0.w;
    s1.x = a1.x * 0.25f + mk1.x;  s1.y = a1.y * 0.25f + mk1.y;
    s1.z = a1.z * 0.25f + mk1.z;  s1.w = a1.w * 0.25f + mk1.w;
    float mh = fmaxf(fmaxf(fmaxf(s0.x, s0.y), fmaxf(s0.z, s0.w)),
                     fmaxf(fmaxf(s1.x, s1.y), fmaxf(s1.z, s1.w)));
    for (int o = 32; o; o >>= 1) mh = fmaxf(mh, __shfl_xor(mh, o));
    float4 e0, e1;
    e0.x = expf(s0.x - mh); e0.y = expf(s0.y - mh);
    e0.z = expf(s0.z - mh); e0.w = expf(s0.w - mh);
    e1.x = expf(s1.x - mh); e1.y = expf(s1.y - mh);
    e1.z = expf(s1.z - mh); e1.w = expf(s1.w - mh);
    float sden = ((e0.x + e0.y) + (e0.z + e0.w)) + ((e1.x + e1.y) + (e1.z + e1.w));
    for (int o = 32; o; o >>= 1) sden += __shfl_xor(sden, o);
    const float inv = 1.0f / sden;
    // ---- (C) PV partials, 4 d-groups of 4 (bounded load regs)
    float ps[16];
#pragma unroll
    for (int dg = 0; dg < 4; ++dg) {
      float4 va[4], vb[4];
#pragma unroll
      for (int u = 0; u < 4; ++u) {
        va[u] = VtB[(h * 16 + dg * 4 + u) * 128 + l];
        vb[u] = VtB[(h * 16 + dg * 4 + u) * 128 + 64 + l];
      }
#pragma unroll
      for (int u = 0; u < 4; ++u) {
        ps[dg * 4 + u] = e0.x * va[u].x + e0.y * va[u].y + e0.z * va[u].z + e0.w * va[u].w
                       + e1.x * vb[u].x + e1.y * vb[u].y + e1.z * vb[u].z + e1.w * vb[u].w;
      }
    }
#pragma unroll
    for (int d = 0; d < 16; ++d) pv[w][l * 17 + d] = ps[d];
    asm volatile("s_waitcnt lgkmcnt(0)" ::: "memory");
    float sum = 0.0f;
#pragma unroll
    for (int j = 0; j < 16; ++j)
      sum += pv[w][((l >> 4) * 16 + j) * 17 + (l & 15)];
    sum += __shfl_xor(sum, 16);
    sum += __shfl_xor(sum, 32);
    if (l < 16) att_s[h * 16 + l] = sum * inv;
    __syncthreads();                                   // barrier 1
    // ---- (E) logits = att . KnW[n] ; gumbel; per-wave records
    float lg, zv;
    {
      const float4* att4 = reinterpret_cast<const float4*>(att_s);
      const float* kc = knB + t;
      float acc = 0.0f, acc2 = 0.0f;
#pragma unroll 8
      for (int k4 = 0; k4 < 32; ++k4) {
        float4 av = att4[k4];
        acc  += av.x * kc[(size_t)(4 * k4 + 0) * 512];
        acc  += av.y * kc[(size_t)(4 * k4 + 1) * 512];
        acc2 += av.z * kc[(size_t)(4 * k4 + 2) * 512];
        acc2 += av.w * kc[(size_t)(4 * k4 + 3) * 512];
      }
      const float lraw = (acc + acc2) / 11.313708498984761f;  // / sqrt(128)
      lg = tanhf(lraw) * 10.0f + emask;                       // -inf if masked
      l_lds[t] = lg;
      unsigned x0 = 0u, x1 = (unsigned)(b * 512 + t);
      const uint2 kk = keys[i];
      threefry2x32(kk.x, kk.y, x0, x1);
      const unsigned bits = x0 ^ x1;
      float f = __uint_as_float((bits >> 9) | 0x3f800000u) - 1.0f;
      f = f + TINYF;
      f = fmaxf(TINYF, f);
      zv = lg + (-logf(-logf(f)));
    }
    {
      float z = zv; int zi = t;
      float mm = lg;
      for (int o = 32; o; o >>= 1) {
        float oz = __shfl_xor(z, o); int oi = __shfl_xor(zi, o);
        if (oz > z || (oz == z && oi < zi)) { z = oz; zi = oi; }
        mm = fmaxf(mm, __shfl_xor(mm, o));
      }
      float e = expf(lg - mm);             // NaN if wave fully masked (guarded)
      for (int o = 32; o; o >>= 1) e += __shfl_xor(e, o);
      if (l == 0) { redZ[w] = z; redI[w] = zi; redM[w] = mm; redD[w] = e; }
    }
    __syncthreads();                                   // barrier 2
    // ---- every thread combines the 8 wave records (uniform result)
    float bz = redZ[0]; int a = redI[0]; float M = redM[0];
#pragma unroll
    for (int ww = 1; ww < 8; ++ww) {
      float oz = redZ[ww]; int oi = redI[ww];
      if (oz > bz || (oz == bz && oi < a)) { bz = oz; a = oi; }
      M = fmaxf(M, redM[ww]);
    }
    float den = 0.0f;
#pragma unroll
    for (int ww = 0; ww < 8; ++ww) {
      float mw = redM[ww];
      if (mw != NEGINF) den += redD[ww] * expf(mw - M);
    }
    if (t == 0) {
      out_probs[i * 64 + b] = expf(l_lds[a] - M) / den;
      out_act[i * 64 + b] = (float)a;
    }
    ap = a;
    if (i == 0) af = a;
    const int n0 = l << 2;
    mk0.x = (a == n0)       ? NEGINF : mk0.x;
    mk0.y = (a == n0 + 1)   ? NEGINF : mk0.y;
    mk0.z = (a == n0 + 2)   ? NEGINF : mk0.z;
    mk0.w = (a == n0 + 3)   ? NEGINF : mk0.w;
    mk1.x = (a == 256 + n0)     ? NEGINF : mk1.x;
    mk1.y = (a == 256 + n0 + 1) ? NEGINF : mk1.y;
    mk1.z = (a == 256 + n0 + 2) ? NEGINF : mk1.z;
    mk1.w = (a == 256 + n0 + 3) ? NEGINF : mk1.w;
    emask = (a == t) ? NEGINF : emask;
  }
}

// ===========================================================================
extern "C" void kernel_launch(void* const* d_in, const int* in_sizes, int n_in,
                              void* d_out, int out_size, void* d_ws, size_t ws_size,
                              hipStream_t stream) {
  const float* problems = (const float*)d_in[0];
  const float* embed_W  = (const float*)d_in[1];
  const float* embed_b  = (const float*)d_in[2];
  const float* enc_Wq   = (const float*)d_in[3];
  const float* enc_Wk   = (const float*)d_in[4];
  const float* enc_Wv   = (const float*)d_in[5];
  const float* enc_Wo   = (const float*)d_in[6];
  const float* ln1g     = (const float*)d_in[7];
  const float* ln1b     = (const float*)d_in[8];
  const float* ffW1     = (const float*)d_in[9];
  const float* ffb1     = (const float*)d_in[10];
  const float* ffW2     = (const float*)d_in[11];
  const float* ffb2     = (const float*)d_in[12];
  const float* ln2g     = (const float*)d_in[13];
  const float* ln2b     = (const float*)d_in[14];
  const float* graph_W  = (const float*)d_in[15];
  const float* node_W   = (const float*)d_in[16];
  const float* dec_Wq   = (const float*)d_in[17];
  const float* dec_Wk   = (const float*)d_in[18];
  const float* dec_Wv   = (const float*)d_in[19];
  const float* dec_Wo   = (const float*)d_in[20];
  const float* W_v_f    = (const float*)d_in[21];
  const float* W_v_l    = (const float*)d_in[22];

  float* ws = (float*)d_ws;
  const size_t SZ = (size_t)64 * 512 * 128;      // 16 MB each
  float* X  = ws;                                 // node states / KnWT at end
  float* Y  = ws + SZ;                            // tmp; later Q-prefolds
  float* Qb = ws + 2 * SZ;                        // Q proj; later Kt
  float* Kb = ws + 3 * SZ;                        // K proj; FFN H; later Vt
  float* Vb = ws + 4 * SZ;                        // V proj; FFN H hi; later kn
  float* NM = ws + 5 * SZ;
  float* GC = NM + 64 * 128;

  float* QG  = Y;                                 // [64,128]
  float* QL  = Y + 8192;                          // [512,128]
  float* QF  = Y + 8192 + 65536;                  // [512,128]
  float* QL0 = Y + 8192 + 131072;                 // [128]
  float* QF0 = QL0 + 128;                         // [128]

  float* out       = (float*)d_out;
  float* out_probs = out;                         // [512,64]
  float* out_act   = out + 512 * 64;              // [512,64] as float

  k_embed<<<16384, 256, 0, stream>>>(problems, embed_W, embed_b, X);

  for (int i = 0; i < 3; ++i) {
    const float* Wqi = enc_Wq + (size_t)i * 16384;
    const float* Wki = enc_Wk + (size_t)i * 16384;
    const float* Wvi = enc_Wv + (size_t)i * 16384;
    const float* Woi = enc_Wo + (size_t)i * 16384;
    k_gemm64<<<dim3(512, 2), 256, 0, stream>>>(X, 128, Wqi, 128, nullptr, nullptr, Qb, 128, 128, 0);
    k_gemm64<<<dim3(512, 2), 256, 0, stream>>>(X, 128, Wki, 128, nullptr, nullptr, Kb, 128, 128, 0);
    k_gemm64<<<dim3(512, 2), 256, 0, stream>>>(X, 128, Wvi, 128, nullptr, nullptr, Vb, 128, 128, 0);
    k_attn_enc<<<512, 512, 0, stream>>>(Qb, Kb, Vb, Y);
    k_gemm64<<<dim3(512, 2), 256, 0, stream>>>(Y, 128, Woi, 128, nullptr, X, Qb, 128, 128, GEP_ADDR);
    k_ln<<<8192, 256, 0, stream>>>(Qb, ln1g + i * 128, ln1b + i * 128, X, 32768);
    // FFN via two 256-wide hidden halves staged in Kb..Vb (32 MB contiguous)
    float* H = Kb;
    for (int half = 0; half < 2; ++half) {
      k_gemm64<<<dim3(512, 4), 256, 0, stream>>>(
          X, 128, ffW1 + (size_t)i * 65536 + half * 256, 512,
          ffb1 + i * 512 + half * 256, nullptr, H, 256, 128, GEP_BIAS | GEP_RELU);
      k_gemm64<<<dim3(512, 2), 256, 0, stream>>>(
          H, 256, ffW2 + (size_t)i * 65536 + (size_t)half * 32768, 128,
          ffb2 + i * 128, X, Y, 128, 256,
          half == 0 ? (GEP_BIAS | GEP_ADDR) : GEP_ACC);
    }
    k_ln<<<8192, 256, 0, stream>>>(Y, ln2g + i * 128, ln2b + i * 128, X, 32768);
  }

  // ---- decoder precompute (X = node_context until the last GEMM) ----
  k_mean<<<64, 128, 0, stream>>>(X, NM);
  k_gemm128<<<dim3(4, 8), 256, 0, stream>>>(NM, graph_W, nullptr, GC, 64);
  k_gemm128<<<dim3(4, 8), 256, 0, stream>>>(GC, dec_Wq, nullptr, QG, 64);
  k_gemm64<<<dim3(8, 2), 256, 0, stream>>>(X, 128, dec_Wq + 16384, 128, nullptr, nullptr, QL, 128, 128, 0);
  k_gemm64<<<dim3(8, 2), 256, 0, stream>>>(X, 128, dec_Wq + 32768, 128, nullptr, nullptr, QF, 128, 128, 0);
  k_gemm128<<<dim3(1, 8), 256, 0, stream>>>(W_v_l, dec_Wq + 16384, nullptr, QL0, 1);
  k_gemm128<<<dim3(1, 8), 256, 0, stream>>>(W_v_f, dec_Wq + 32768, nullptr, QF0, 1);
  k_gemm64<<<dim3(512, 2), 256, 0, stream>>>(X, 128, dec_Wk, 128, nullptr, nullptr, Qb, 128, 128, GEP_TST);   // Kt
  k_gemm64<<<dim3(512, 2), 256, 0, stream>>>(X, 128, dec_Wv, 128, nullptr, nullptr, Kb, 128, 128, GEP_TST);   // Vt
  k_gemm64<<<dim3(512, 2), 256, 0, stream>>>(X, 128, node_W, 128, nullptr, nullptr, Vb, 128, 128, 0);         // kn
  k_gemm64<<<dim3(512, 2), 256, 0, stream>>>(Vb, 128, dec_Wo, 128, nullptr, nullptr, X, 128, 128,
                                             GEP_WT | GEP_TST);                                               // KnWT

  k_decoder<<<64, 512, 0, stream>>>(Qb, Kb, X, QG, QL, QF, QL0, QF0,
                                    out_probs, out_act);
}